// Round 10
// baseline (284.104 us; speedup 1.0000x reference)
//
#include <hip/hip_runtime.h>

// ---------------------------------------------------------------------------
// MultiScaleFeatureFusion — R10: 5-dispatch pipeline.
//   scale0: x1 [4,512,16,16]  d=64 C=512 hs=16 Ns=256  R=161
//   scale1: x2 [4,256,32,32]  d=32 C=256 hs=32 Ns=1024 R=97
//   scale2: x3 [4,128,64,64]  d=16 C=128 hs=64 Ns=4096 R=65
// u -> proj (sw-pipelined x loads) -> mid (upsample-s + kpack + lnat tables,
// log2e folded) -> attn (attnf32 + attnf16 4-oy chunks + attn2 split-bf16
// MFMA, one dispatch) -> final (combine + fusion). No-max softmax (exact:
// logits bounded; common scale cancels in Sw/Sn).
// ---------------------------------------------------------------------------

#define BB 4
#define LOG2E 1.44269504088896340736f

typedef __attribute__((ext_vector_type(8))) short short8;
typedef __attribute__((ext_vector_type(4))) float f32x4;

static constexpr int OFF_UP0 = 0;                        // [4][512]
static constexpr int OFF_UP1 = OFF_UP0 + 4 * 512;
static constexpr int OFF_UP2 = OFF_UP1 + 4 * 256;
static constexpr int OFF_UB0 = OFF_UP2 + 4 * 128;        // [4] each
static constexpr int OFF_UB1 = OFF_UB0 + 4;
static constexpr int OFF_UB2 = OFF_UB1 + 4;
static constexpr int OFF_PROJ0 = OFF_UB2 + 4;
static constexpr int OFF_PROJ1 = OFF_PROJ0 + BB * 161 * 256;
static constexpr int OFF_PROJ2 = OFF_PROJ1 + BB * 97 * 1024;
static constexpr int OFF_SBIG0 = OFF_PROJ2 + BB * 65 * 4096;   // [b][4096]
static constexpr int OFF_SBIG1 = OFF_SBIG0 + BB * 4096;        // [b][4096]
static constexpr int OFF_LN0   = OFF_SBIG1 + BB * 4096;        // [b][256][256] (x log2e)
static constexpr int OFF_LN1   = OFF_LN0 + BB * 256 * 256;     // [b][1024][1024] (x log2e)
static constexpr int PS01 = BB * 16 * 4096;
static constexpr int PS2  = BB * 4 * 4096;
static constexpr int OFF_PSN0 = OFF_LN1 + BB * 1024 * 1024;
static constexpr int OFF_PSW0 = OFF_PSN0 + PS01;
static constexpr int OFF_PSN1 = OFF_PSW0 + PS01;
static constexpr int OFF_PSW1 = OFF_PSN1 + PS01;
static constexpr int OFF_PSN2 = OFF_PSW1 + PS01;
static constexpr int OFF_PSW2 = OFF_PSN2 + PS2;
static constexpr int OFF_KP   = OFF_PSW2 + PS2;                // 4*4096*32 ushort

// --------------------------- u partials ------------------------------------
struct UArgs {
    const float *wv0, *wa0, *bv0;
    const float *wv1, *wa1, *bv1;
    const float *wv2, *wa2, *bv2;
    float* ws;
};

__global__ void u_kernel(UArgs A) {
    __shared__ float red[256];
    int idx = blockIdx.x, tid = threadIdx.x;
    int C, cit, chunk;
    const float *wv, *wa, *bv;
    float *up, *ub;
    if (idx < 32) {
        C = 512; cit = idx >> 2; chunk = idx & 3;
        wv = A.wv0; wa = A.wa0; bv = A.bv0;
        up = A.ws + OFF_UP0; ub = A.ws + OFF_UB0;
    } else if (idx < 48) {
        int i2 = idx - 32;
        C = 256; cit = i2 >> 2; chunk = i2 & 3;
        wv = A.wv1; wa = A.wa1; bv = A.bv1;
        up = A.ws + OFF_UP1; ub = A.ws + OFF_UB1;
    } else {
        int i2 = idx - 48;
        C = 128; cit = i2 >> 2; chunk = i2 & 3;
        wv = A.wv2; wa = A.wa2; bv = A.bv2;
        up = A.ws + OFF_UP2; ub = A.ws + OFF_UB2;
    }
    int lci = tid & 63, sub = tid >> 6;
    int ci = cit * 64 + lci;
    int coBeg = chunk * (C >> 2), coEnd = coBeg + (C >> 2);
    float acc = 0.f;
#pragma unroll 4
    for (int co = coBeg + sub; co < coEnd; co += 4)
        acc += wa[co] * wv[(size_t)co * C + ci];
    red[tid] = acc;
    __syncthreads();
    if (sub == 0)
        up[chunk * C + ci] = red[lci] + red[lci + 64] + red[lci + 128] + red[lci + 192];
    if (cit == 0) {
        __syncthreads();
        float bacc = 0.f;
        for (int co = coBeg + tid; co < coEnd; co += 256) bacc += wa[co] * bv[co];
        red[tid] = bacc;
        __syncthreads();
        for (int off = 128; off > 0; off >>= 1) {
            if (tid < off) red[tid] += red[tid + off];
            __syncthreads();
        }
        if (tid == 0) ub[chunk] = red[0];
    }
}

// --------------------------- proj: all scales ------------------------------
// Stages W rows straight from inputs; 4-deep software-pipelined x loads.
struct ProjArgs {
    const float *x0, *x1, *x2;
    const float *wq0, *wk0, *bq0, *bk0;
    const float *wq1, *wk1, *bq1, *bk1;
    const float *wq2, *wk2, *bq2, *bk2;
    const float *w1;
    float* ws;
};

__global__ __launch_bounds__(256) void proj_kernel(ProjArgs A) {
    __shared__ __align__(16) float Wl[512 * 8];   // [c][rr]
    __shared__ float bl[8];
    __shared__ float red[8192];
    int idx = blockIdx.x, tid = threadIdx.x;
    const float *x, *wq, *wk, *bq, *bk, *up, *ub;
    float* out;
    int C, Ns, R, nx, d, w1off, local;
    if (idx < 84) {
        local = idx; x = A.x0; out = A.ws + OFF_PROJ0;
        wq = A.wq0; wk = A.wk0; bq = A.bq0; bk = A.bk0;
        up = A.ws + OFF_UP0; ub = A.ws + OFF_UB0;
        C = 512; Ns = 256; R = 161; nx = 1; d = 64; w1off = 384;
    } else if (idx < 292) {
        local = idx - 84; x = A.x1; out = A.ws + OFF_PROJ1;
        wq = A.wq1; wk = A.wk1; bq = A.bq1; bk = A.bk1;
        up = A.ws + OFF_UP1; ub = A.ws + OFF_UB1;
        C = 256; Ns = 1024; R = 97; nx = 4; d = 32; w1off = 128;
    } else {
        local = idx - 292; x = A.x2; out = A.ws + OFF_PROJ2;
        wq = A.wq2; wk = A.wk2; bq = A.bq2; bk = A.bk2;
        up = A.ws + OFF_UP2; ub = A.ws + OFF_UB2;
        C = 128; Ns = 4096; R = 65; nx = 16; d = 16; w1off = 0;
    }
    int ny = (R + 7) >> 3;
    int pb = nx * ny;
    int b = local / pb;
    int rem = local - b * pb;
    int by = rem / nx;
    int bx = rem - by * nx;
    int r0 = by * 8;
    int nr = min(8, R - r0);
    {
        int rr = tid >> 5, cg = tid & 31;
        int gr = r0 + rr;
        if (gr == 2 * d) {
            for (int c = cg; c < C; c += 32)
                Wl[c * 8 + rr] = up[c] + up[C + c] + up[2 * C + c] + up[3 * C + c];
        } else {
            const float* rowsrc;
            if (gr < d) rowsrc = wq + (size_t)gr * C;
            else if (gr < 2 * d) rowsrc = wk + (size_t)(gr - d) * C;
            else if (gr < R) rowsrc = A.w1 + (size_t)(gr - 2 * d - 1) * 896 + w1off;
            else rowsrc = nullptr;
            if (rowsrc) {
                for (int c = cg; c < C; c += 32) Wl[c * 8 + rr] = rowsrc[c];
            } else {
                for (int c = cg; c < C; c += 32) Wl[c * 8 + rr] = 0.f;
            }
        }
        if (tid < 8) {
            int g2 = r0 + tid;
            float bv2;
            if (g2 < d) bv2 = bq[g2];
            else if (g2 < 2 * d) bv2 = bk[g2 - d];
            else if (g2 == 2 * d) bv2 = ub[0] + ub[1] + ub[2] + ub[3];
            else bv2 = 0.f;
            bl[tid] = bv2;
        }
    }
    __syncthreads();
    int lane = tid & 63, strip = tid >> 6;
    int m0 = bx * 256 + lane * 4;
    const float* xb = x + (size_t)(b * C) * Ns + m0;
    float acc[8][4];
#pragma unroll
    for (int r = 0; r < 8; ++r)
#pragma unroll
        for (int j = 0; j < 4; ++j) acc[r][j] = 0.f;
    // software pipeline: 4 x-loads in flight (c = strip + 4*k, k-tiers of 4)
    float4 buf[4];
#pragma unroll
    for (int j = 0; j < 4; ++j)
        buf[j] = *(const float4*)&xb[(size_t)(strip + 4 * j) * Ns];
    for (int c0 = strip; c0 < C; c0 += 16) {
#pragma unroll
        for (int j = 0; j < 4; ++j) {
            int c = c0 + 4 * j;
            float4 xv = buf[j];
            int cn = c + 16;
            if (cn < C) buf[j] = *(const float4*)&xb[(size_t)cn * Ns];
            float4 w0 = *(const float4*)&Wl[c * 8];
            float4 w1v = *(const float4*)&Wl[c * 8 + 4];
            acc[0][0] += w0.x * xv.x; acc[0][1] += w0.x * xv.y; acc[0][2] += w0.x * xv.z; acc[0][3] += w0.x * xv.w;
            acc[1][0] += w0.y * xv.x; acc[1][1] += w0.y * xv.y; acc[1][2] += w0.y * xv.z; acc[1][3] += w0.y * xv.w;
            acc[2][0] += w0.z * xv.x; acc[2][1] += w0.z * xv.y; acc[2][2] += w0.z * xv.z; acc[2][3] += w0.z * xv.w;
            acc[3][0] += w0.w * xv.x; acc[3][1] += w0.w * xv.y; acc[3][2] += w0.w * xv.z; acc[3][3] += w0.w * xv.w;
            acc[4][0] += w1v.x * xv.x; acc[4][1] += w1v.x * xv.y; acc[4][2] += w1v.x * xv.z; acc[4][3] += w1v.x * xv.w;
            acc[5][0] += w1v.y * xv.x; acc[5][1] += w1v.y * xv.y; acc[5][2] += w1v.y * xv.z; acc[5][3] += w1v.y * xv.w;
            acc[6][0] += w1v.z * xv.x; acc[6][1] += w1v.z * xv.y; acc[6][2] += w1v.z * xv.z; acc[6][3] += w1v.z * xv.w;
            acc[7][0] += w1v.w * xv.x; acc[7][1] += w1v.w * xv.y; acc[7][2] += w1v.w * xv.z; acc[7][3] += w1v.w * xv.w;
        }
    }
#pragma unroll
    for (int r = 0; r < 8; ++r)
#pragma unroll
        for (int j = 0; j < 4; ++j)
            red[((r * 4 + j) * 4 + strip) * 64 + lane] = acc[r][j];
    __syncthreads();
    int g = tid >> 6;
    for (int rr = g * 2; rr < g * 2 + 2; ++rr) {
        if (rr >= nr) continue;
        float v[4];
#pragma unroll
        for (int j = 0; j < 4; ++j) {
            int base = (rr * 4 + j) * 4 * 64 + lane;
            v[j] = red[base] + red[base + 64] + red[base + 128] + red[base + 192] + bl[rr];
        }
        *(float4*)&out[(size_t)(b * R + r0 + rr) * Ns + m0] = make_float4(v[0], v[1], v[2], v[3]);
    }
}

// --------------------------- lnat body (device) ----------------------------
// L[b][ns][ms] = LOG2E * q_nat[ns].k_nat[ms]; block = 8 ns x NS ms.
template <int D, int NS, int NM>
__device__ void lnat_body(const float* __restrict__ proj, int R, float* __restrict__ L,
                          int ns_blk, int b, int tid, float* ql) {
    const float* pb = proj + (size_t)b * R * NS;
    int ns0 = ns_blk * 8;
    for (int i = tid; i < D * 8; i += 256)
        ql[i] = pb[(size_t)(i >> 3) * NS + ns0 + (i & 7)] * LOG2E;
    __syncthreads();
    float acc[8][NM];
#pragma unroll
    for (int ns = 0; ns < 8; ++ns)
#pragma unroll
        for (int j = 0; j < NM; ++j) acc[ns][j] = 0.f;
    const float* kp = pb + (size_t)D * NS + tid;
    for (int dd = 0; dd < D; ++dd) {
        float kv[NM];
#pragma unroll
        for (int j = 0; j < NM; ++j) kv[j] = kp[(size_t)dd * NS + j * 256];
        float4 qa = *(const float4*)&ql[dd * 8];
        float4 qb = *(const float4*)&ql[dd * 8 + 4];
        float qv[8] = {qa.x, qa.y, qa.z, qa.w, qb.x, qb.y, qb.z, qb.w};
#pragma unroll
        for (int ns = 0; ns < 8; ++ns)
#pragma unroll
            for (int j = 0; j < NM; ++j) acc[ns][j] += qv[ns] * kv[j];
    }
#pragma unroll
    for (int ns = 0; ns < 8; ++ns)
#pragma unroll
        for (int j = 0; j < NM; ++j)
            L[((size_t)b * NS + ns0 + ns) * NS + tid + j * 256] = acc[ns][j];
}

// --------------------------- mid: upsample-s + kpack + lnat ----------------
__global__ __launch_bounds__(256) void mid_kernel(float* ws) {
    __shared__ __align__(16) float ql[512];
    int idx = blockIdx.x, tid = threadIdx.x;
    if (idx < 128) {
        // upsample s rows
        int gi = idx * 256 + tid;
        int seg = gi >> 14;
        int li = gi & 16383;
        int b = li >> 12, n = li & 4095;
        const float* src;
        float* dst;
        int hs;
        if (seg == 0) { src = ws + OFF_PROJ0 + (b * 161 + 128) * 256;  dst = ws + OFF_SBIG0; hs = 16; }
        else          { src = ws + OFF_PROJ1 + (b * 97 + 64) * 1024;   dst = ws + OFF_SBIG1; hs = 32; }
        int oy = n >> 6, ox = n & 63;
        float f = (float)(hs - 1) / 63.0f;
        float cy = oy * f, cx = ox * f;
        int iy0 = min((int)cy, hs - 2);
        int ix0 = min((int)cx, hs - 2);
        float wy = cy - iy0, wx = cx - ix0;
        float v00 = src[iy0 * hs + ix0], v01 = src[iy0 * hs + ix0 + 1];
        float v10 = src[(iy0 + 1) * hs + ix0], v11 = src[(iy0 + 1) * hs + ix0 + 1];
        float t0 = v00 + wx * (v01 - v00), t1 = v10 + wx * (v11 - v10);
        dst[b * 4096 + n] = t0 + wy * (t1 - t0);
    } else if (idx < 192) {
        // kpack (scale2, bf16 hi/lo)
        int gi = (idx - 128) * 256 + tid;  // 0..16383
        int b = gi >> 12, m = gi & 4095;
        const float* kb = ws + OFF_PROJ2 + ((size_t)b * 65 + 16) * 4096 + m;
        ushort* kp = (ushort*)(ws + OFF_KP);
        ushort outv[32];
#pragma unroll
        for (int d = 0; d < 16; ++d) {
            float f = kb[(size_t)d * 4096];
            unsigned u = __float_as_uint(f);
            unsigned hi = u >> 16;
            float r = f - __uint_as_float(hi << 16);
            outv[d] = (ushort)hi;
            outv[16 + d] = (ushort)(__float_as_uint(r) >> 16);
        }
        ushort* dst = kp + (size_t)gi * 32;
#pragma unroll
        for (int i = 0; i < 4; ++i)
            ((uint4*)dst)[i] = ((const uint4*)outv)[i];
    } else if (idx < 320) {
        int local = idx - 192;  // 128 = 32 ns-blocks x 4 b
        lnat_body<64, 256, 1>(ws + OFF_PROJ0, 161, ws + OFF_LN0,
                              local & 31, local >> 5, tid, ql);
    } else {
        int local = idx - 320;  // 512 = 128 ns-blocks x 4 b
        lnat_body<32, 1024, 4>(ws + OFF_PROJ1, 97, ws + OFF_LN1,
                               local & 127, local >> 7, tid, ql);
    }
}

// --------------------------- attnf body (device) ---------------------------
// Block = 4 output m-rows (oyc), one n-row (noy), b. Phase 1: build 4 native
// m-logit rows R[iyr][ms][nox] = q-bilerp of L in LDS. Phase 2: strip = one
// oy; y-lerp + x-lerp + exp2 accumulate. L pre-scaled by log2e.
template <int HS>
__device__ void attnf_body(const float* __restrict__ L, const float* __restrict__ sbig,
                           float* __restrict__ pSn, float* __restrict__ pSw,
                           int oyc, int noy, int b, int tid, float* smem) {
    constexpr int NS = HS * HS;
    constexpr float f = (float)(HS - 1) / 63.0f;
    float* Rl = smem;                    // [4][HS][64]
    float* sl = smem + 4 * HS * 64;      // [256]
    float* redn = sl + 256;              // [256]
    float* redw = redn + 256;            // [256]
    float cyq = noy * f;
    int iyq = min((int)cyq, HS - 2);
    float wyq = cyq - (float)iyq;
    int iyLo = (int)(oyc * 4 * f);
    const float* Lb = L + (size_t)b * NS * NS;
    sl[tid] = sbig[b * 4096 + oyc * 256 + tid];
    // phase 1
    constexpr int MS4 = HS / 4;
    constexpr int NT = 64 * MS4 * 4;
#pragma unroll
    for (int t = tid; t < NT; t += 256) {
        int nox = t & 63;
        int rest = t >> 6;
        int ms4 = rest % MS4;
        int iyr = rest / MS4;
        float cx = nox * f;
        int ixq = min((int)cx, HS - 2);
        float wx = cx - (float)ixq;
        float w00 = (1.f - wyq) * (1.f - wx), w01 = (1.f - wyq) * wx;
        float w10 = wyq * (1.f - wx), w11 = wyq * wx;
        int iy = min(iyLo + iyr, HS - 1);
        const float* base = Lb + (size_t)(iyq * HS + ixq) * NS + iy * HS + ms4 * 4;
        float4 a = *(const float4*)base;
        float4 bq = *(const float4*)(base + NS);
        float4 c = *(const float4*)(base + (size_t)HS * NS);
        float4 d = *(const float4*)(base + (size_t)HS * NS + NS);
        int ro = (iyr * HS + ms4 * 4) * 64 + nox;
        Rl[ro]       = w00 * a.x + w01 * bq.x + w10 * c.x + w11 * d.x;
        Rl[ro + 64]  = w00 * a.y + w01 * bq.y + w10 * c.y + w11 * d.y;
        Rl[ro + 128] = w00 * a.z + w01 * bq.z + w10 * c.z + w11 * d.z;
        Rl[ro + 192] = w00 * a.w + w01 * bq.w + w10 * c.w + w11 * d.w;
    }
    __syncthreads();
    // phase 2: strip = one oy
    int nox = tid & 63, strip = tid >> 6;
    int oy = oyc * 4 + strip;
    float cy = oy * f;
    int iy0 = min((int)cy, HS - 2);
    float wy = cy - (float)iy0;
    int iyr = iy0 - iyLo;
    float Lr[HS];
#pragma unroll
    for (int ms = 0; ms < HS; ++ms) {
        float r0 = Rl[(iyr * HS + ms) * 64 + nox];
        float r1 = Rl[((iyr + 1) * HS + ms) * 64 + nox];
        Lr[ms] = r0 + wy * (r1 - r0);
    }
    float Sn = 0.f, Sw = 0.f;
    int so = strip * 64;
#pragma unroll
    for (int ox = 0; ox < 64; ++ox) {
        float cx = ox * f;
        int ix0 = min((int)cx, HS - 2);
        float wx = cx - (float)ix0;
        float v = Lr[ix0] + wx * (Lr[ix0 + 1] - Lr[ix0]);
        float e = exp2f(v);
        Sn += e;
        Sw += e * sl[so + ox];
    }
    redn[tid] = Sn;
    redw[tid] = Sw;
    __syncthreads();
    if (strip == 0) {
        float St = redn[nox] + redn[64 + nox] + redn[128 + nox] + redn[192 + nox];
        float Wt = redw[nox] + redw[64 + nox] + redw[128 + nox] + redw[192 + nox];
        int pidx = (b * 16 + oyc) * 4096 + noy * 64 + nox;
        pSn[pidx] = St;
        pSw[pidx] = Wt;
    }
}

// --------------------------- attn2 body (device, MFMA) ---------------------
__device__ void attn2_body(const float* __restrict__ ws, const ushort* __restrict__ kp,
                           float* __restrict__ pSn, float* __restrict__ pSw,
                           int nblk, int mc, int b, int tid) {
    int wave = tid >> 6, lane = tid & 63;
    int cc = lane & 15, quad = lane >> 4;
    int n0 = (nblk * 4 + wave) * 16;
    const float* bb = ws + OFF_PROJ2 + (size_t)b * 65 * 4096;
    short8 afrag;
    const float* qb = bb + n0 + cc;
    int dbase = (quad & 1) * 8;
#pragma unroll
    for (int j = 0; j < 8; ++j) {
        float f = qb[(size_t)(dbase + j) * 4096] * LOG2E;
        unsigned u = __float_as_uint(f);
        unsigned hi = u >> 16;
        float r = f - __uint_as_float(hi << 16);
        unsigned lo = __float_as_uint(r) >> 16;
        afrag[j] = (short)((quad < 2) ? hi : lo);
    }
    const ushort* kpb = kp + (size_t)b * 4096 * 32;
    const float* srow = bb + (size_t)32 * 4096;
    float Sn[4] = {0.f, 0.f, 0.f, 0.f};
    float Sw[4] = {0.f, 0.f, 0.f, 0.f};
    int hoff = (quad & 1) * 8;
    int mbase = mc * 1024;
    for (int mt = 0; mt < 64; ++mt) {
        int m0 = mbase + mt * 16;
        const ushort* kc = kpb + (size_t)(m0 + cc) * 32;
        short8 b1 = *(const short8*)(kc + hoff);
        short8 b2 = *(const short8*)(kc + 16 + hoff);
        float sv = srow[m0 + cc];
        f32x4 c = {0.f, 0.f, 0.f, 0.f};
        c = __builtin_amdgcn_mfma_f32_16x16x32_bf16(afrag, b2, c, 0, 0, 0);
        c = __builtin_amdgcn_mfma_f32_16x16x32_bf16(afrag, b1, c, 0, 0, 0);
#pragma unroll
        for (int r = 0; r < 4; ++r) {
            float e = exp2f(c[r]);
            Sn[r] += e;
            Sw[r] += e * sv;
        }
    }
#pragma unroll
    for (int mask = 1; mask < 16; mask <<= 1) {
#pragma unroll
        for (int r = 0; r < 4; ++r) {
            Sn[r] += __shfl_xor(Sn[r], mask, 64);
            Sw[r] += __shfl_xor(Sw[r], mask, 64);
        }
    }
    if (cc == 0) {
        int n = n0 + quad * 4;
        int pidx = (b * 4 + mc) * 4096 + n;
        *(float4*)&pSn[pidx] = make_float4(Sn[0], Sn[1], Sn[2], Sn[3]);
        *(float4*)&pSw[pidx] = make_float4(Sw[0], Sw[1], Sw[2], Sw[3]);
    }
}

// --------------------------- attn: all three scales ------------------------
// blocks [0,4096): attnf32; [4096,8192): attnf16; [8192,9216): attn2 MFMA.
__global__ __launch_bounds__(256) void attn_kernel(float* ws) {
    __shared__ __align__(16) float smem[4 * 32 * 64 + 768];
    int idx = blockIdx.x, tid = threadIdx.x;
    if (idx < 4096) {
        int oyc = idx & 15, noy = (idx >> 4) & 63, b = idx >> 10;
        attnf_body<32>(ws + OFF_LN1, ws + OFF_SBIG1,
                       ws + OFF_PSN1, ws + OFF_PSW1, oyc, noy, b, tid, smem);
    } else if (idx < 8192) {
        int li = idx - 4096;
        int oyc = li & 15, noy = (li >> 4) & 63, b = li >> 10;
        attnf_body<16>(ws + OFF_LN0, ws + OFF_SBIG0,
                       ws + OFF_PSN0, ws + OFF_PSW0, oyc, noy, b, tid, smem);
    } else {
        int li = idx - 8192;
        int nblk = li & 63, mc = (li >> 6) & 3, b = li >> 8;
        attn2_body(ws, (const ushort*)(ws + OFF_KP),
                   ws + OFF_PSN2, ws + OFF_PSW2, nblk, mc, b, tid);
    }
}

// --------------------------- final: combine + fusion -----------------------
__global__ __launch_bounds__(256) void final_kernel(const float* __restrict__ ws,
                                                    const float* __restrict__ ba0,
                                                    const float* __restrict__ ba1,
                                                    const float* __restrict__ ba2,
                                                    const float* __restrict__ b1,
                                                    const float* __restrict__ w2,
                                                    const float* __restrict__ b2,
                                                    float* __restrict__ out) {
    __shared__ float lb1[32], lw2[32];
    int tid = threadIdx.x;
    if (tid < 32) { lb1[tid] = b1[tid]; lw2[tid] = w2[tid]; }
    __syncthreads();
    int b = blockIdx.y;
    int n = blockIdx.x * 256 + tid;
    const float* pSns[3] = {ws + OFF_PSN0, ws + OFF_PSN1, ws + OFF_PSN2};
    const float* pSws[3] = {ws + OFF_PSW0, ws + OFF_PSW1, ws + OFF_PSW2};
    const int ncs[3] = {16, 16, 4};
    float aval[3];
#pragma unroll
    for (int s = 0; s < 3; ++s) {
        int nc = ncs[s];
        float Sn = 0.f, Sw = 0.f;
        for (int ch = 0; ch < nc; ++ch) {
            int pi = (b * nc + ch) * 4096 + n;
            Sn += pSns[s][pi];
            Sw += pSws[s][pi];
        }
        float bav = (s == 0) ? ba0[0] : (s == 1) ? ba1[0] : ba2[0];
        aval[s] = Sw / Sn + bav;
    }
    float prod = aval[0] * aval[1] * aval[2];
    int oy = n >> 6, ox = n & 63;
    float f0 = 15.0f / 63.0f;
    float cy0 = oy * f0, cx0 = ox * f0;
    int iy0 = min((int)cy0, 14), ix0 = min((int)cx0, 14);
    float wy0 = cy0 - iy0, wx0 = cx0 - ix0;
    float f1 = 31.0f / 63.0f;
    float cy1 = oy * f1, cx1 = ox * f1;
    int iy1 = min((int)cy1, 30), ix1 = min((int)cx1, 30);
    float wy1 = cy1 - iy1, wx1 = cx1 - ix1;
    const float* g0b = ws + OFF_PROJ0 + (b * 161 + 129) * 256;
    const float* g1b = ws + OFF_PROJ1 + (b * 97 + 65) * 1024;
    const float* g2b = ws + OFF_PROJ2 + (b * 65 + 33) * 4096;
    float outv = 0.f;
#pragma unroll 4
    for (int j = 0; j < 32; ++j) {
        const float* p0 = g0b + j * 256;
        float v0 = (1.f - wy0) * ((1.f - wx0) * p0[iy0 * 16 + ix0] + wx0 * p0[iy0 * 16 + ix0 + 1]) +
                   wy0 * ((1.f - wx0) * p0[(iy0 + 1) * 16 + ix0] + wx0 * p0[(iy0 + 1) * 16 + ix0 + 1]);
        const float* p1 = g1b + j * 1024;
        float v1 = (1.f - wy1) * ((1.f - wx1) * p1[iy1 * 32 + ix1] + wx1 * p1[iy1 * 32 + ix1 + 1]) +
                   wy1 * ((1.f - wx1) * p1[(iy1 + 1) * 32 + ix1] + wx1 * p1[(iy1 + 1) * 32 + ix1 + 1]);
        float g = g2b[j * 4096 + n] + v0 + v1;
        float h = fmaxf(prod * g + lb1[j], 0.f);
        outv += lw2[j] * h;
    }
    out[b * 4096 + n] = outv + b2[0];
}

// ---------------------------------------------------------------------------
extern "C" void kernel_launch(void* const* d_in, const int* in_sizes, int n_in,
                              void* d_out, int out_size, void* d_ws, size_t ws_size,
                              hipStream_t stream) {
    const float* x3 = (const float*)d_in[0];
    const float* x2 = (const float*)d_in[1];
    const float* x1 = (const float*)d_in[2];
    const float* W[24];
    for (int i = 0; i < 24; ++i) W[i] = (const float*)d_in[3 + i];
    const float* w1 = (const float*)d_in[27];
    const float* b1 = (const float*)d_in[28];
    const float* w2 = (const float*)d_in[29];
    const float* b2 = (const float*)d_in[30];
    float* ws = (float*)d_ws;
    float* out = (float*)d_out;

    UArgs ua;
    ua.wv0 = W[4];  ua.wa0 = W[6];  ua.bv0 = W[5];
    ua.wv1 = W[12]; ua.wa1 = W[14]; ua.bv1 = W[13];
    ua.wv2 = W[20]; ua.wa2 = W[22]; ua.bv2 = W[21];
    ua.ws = ws;
    u_kernel<<<56, 256, 0, stream>>>(ua);

    ProjArgs ja;
    ja.x0 = x1; ja.x1 = x2; ja.x2 = x3;
    ja.wq0 = W[0];  ja.wk0 = W[2];  ja.bq0 = W[1];  ja.bk0 = W[3];
    ja.wq1 = W[8];  ja.wk1 = W[10]; ja.bq1 = W[9];  ja.bk1 = W[11];
    ja.wq2 = W[16]; ja.wk2 = W[18]; ja.bq2 = W[17]; ja.bk2 = W[19];
    ja.w1 = w1; ja.ws = ws;
    proj_kernel<<<868, 256, 0, stream>>>(ja);

    mid_kernel<<<832, 256, 0, stream>>>(ws);

    attn_kernel<<<9216, 256, 0, stream>>>(ws);

    final_kernel<<<dim3(16, BB), 256, 0, stream>>>(ws, W[7], W[15], W[23],
                                                   b1, w2, b2, out);
}